// Round 1
// baseline (528.943 us; speedup 1.0000x reference)
//
#include <hip/hip_runtime.h>
#include <hip/hip_bf16.h>
#include <stdint.h>

#define B_SZ 16
#define L_SEQ 8192
#define D_MOD 512
#define N_H 8
#define D_H 64
#define KSEL 100

// ---------------------------------------------------------------------------
// Kernel 1: exact top-100 selection per batch row via radix select.
// hawkes_weights are uniform [0,1) => non-negative => uint bit pattern is
// monotonic in value. Output set order does not matter (downstream is
// permutation-invariant); ties broken by lowest index (matches jax stability).
// ---------------------------------------------------------------------------
__global__ __launch_bounds__(256) void topk_kernel(const float* __restrict__ w,
                                                   int* __restrict__ idx_out) {
    const int b = blockIdx.x;
    const float* wb = w + (size_t)b * L_SEQ;
    __shared__ uint32_t uval[L_SEQ];
    __shared__ int hist[256];
    __shared__ uint32_t s_thresh;
    __shared__ int s_rem;
    __shared__ int s_cntgt;
    const int t = threadIdx.x;

    for (int i = t; i < L_SEQ; i += 256) uval[i] = __float_as_uint(wb[i]);

    uint32_t prefix = 0, pmask = 0;
    int remaining = KSEL;
    for (int pass = 0; pass < 4; ++pass) {
        const int shift = 24 - 8 * pass;
        hist[t] = 0;
        __syncthreads();
        for (int i = t; i < L_SEQ; i += 256) {
            uint32_t u = uval[i];
            if ((u & pmask) == prefix) atomicAdd(&hist[(u >> shift) & 0xFF], 1);
        }
        __syncthreads();
        if (t == 0) {
            int cum = 0;
            int bin = 255;
            for (; bin > 0; --bin) {
                int h = hist[bin];
                if (cum + h >= remaining) break;
                cum += h;
            }
            s_thresh = prefix | ((uint32_t)bin << shift);
            s_rem = remaining - cum;
        }
        __syncthreads();
        prefix = s_thresh;
        remaining = s_rem;
        pmask |= (uint32_t)0xFF << shift;
        __syncthreads();
    }

    if (t == 0) s_cntgt = 0;
    __syncthreads();
    int* out = idx_out + b * KSEL;
    for (int i = t; i < L_SEQ; i += 256) {
        if (uval[i] > prefix) {
            int p = atomicAdd(&s_cntgt, 1);
            out[p] = i;
        }
    }
    __syncthreads();
    const int cntgt = s_cntgt;  // == KSEL - remaining
    // take `remaining` lowest-index elements equal to threshold (wave 0)
    if (t < 64) {
        int needed = remaining;
        int taken = 0;
        for (int base = 0; base < L_SEQ && needed > 0; base += 64) {
            bool eq = (uval[base + t] == prefix);
            unsigned long long mask = __ballot(eq);
            int before = __popcll(mask & ((1ull << t) - 1ull));
            int c = __popcll(mask);
            int take = c < needed ? c : needed;
            if (eq && before < take) out[cntgt + taken + before] = base + t;
            taken += take;
            needed -= take;
        }
    }
}

// ---------------------------------------------------------------------------
// Kernel 2: one block per (batch, head). Computes
//   Qh = Wq_h @ query + bq_h
//   a  = Qh @ Wk_h                      (fold K-projection into scores)
//   s_j = (a . x_j + Qh.bk_h) * scale
//   p = softmax(s)
//   y  = sum_j p_j x_j                  (fold V-projection out of the sum)
//   attn_h = Wv_h @ y + bv_h
// ---------------------------------------------------------------------------
__global__ __launch_bounds__(256) void attn_kernel(
    const float* __restrict__ mamba, const float* __restrict__ skip,
    const float* __restrict__ Wq, const float* __restrict__ bq,
    const float* __restrict__ Wk, const float* __restrict__ bk,
    const float* __restrict__ Wv, const float* __restrict__ bv,
    const int* __restrict__ idx, float* __restrict__ attn_out) {
    const int b = blockIdx.x >> 3;
    const int h = blockIdx.x & 7;
    const int t = threadIdx.x;
    const int lane = t & 63;
    const int wave = t >> 6;

    __shared__ float s_query[D_MOD];
    __shared__ float s_Qh[D_H];
    __shared__ float s_a[D_MOD];
    __shared__ float s_scores[128];
    __shared__ float s_p[128];
    __shared__ float s_y[D_MOD];
    __shared__ int s_idx[KSEL];
    __shared__ float s_qdotbk;

    const float* q = mamba + ((size_t)b * L_SEQ + (L_SEQ - 1)) * D_MOD;
    for (int i = t; i < D_MOD; i += 256) s_query[i] = q[i];
    for (int i = t; i < KSEL; i += 256) s_idx[i] = idx[b * KSEL + i];
    __syncthreads();

    // Qh: 64 rows of Wq for this head; wave-per-row, lanes split columns.
    const float* Wqh = Wq + (size_t)(h * D_H) * D_MOD;
    for (int d = wave; d < D_H; d += 4) {
        const float4* row4 = (const float4*)(Wqh + (size_t)d * D_MOD);
        const float4* q4 = (const float4*)s_query;
        float4 w0 = row4[lane * 2], w1 = row4[lane * 2 + 1];
        float4 q0 = q4[lane * 2], q1 = q4[lane * 2 + 1];
        float sum = w0.x * q0.x + w0.y * q0.y + w0.z * q0.z + w0.w * q0.w +
                    w1.x * q1.x + w1.y * q1.y + w1.z * q1.z + w1.w * q1.w;
        #pragma unroll
        for (int off = 32; off > 0; off >>= 1) sum += __shfl_down(sum, off);
        if (lane == 0) s_Qh[d] = sum + bq[h * D_H + d];
    }
    __syncthreads();

    if (wave == 0) {
        float v = s_Qh[lane] * bk[h * D_H + lane];
        #pragma unroll
        for (int off = 32; off > 0; off >>= 1) v += __shfl_down(v, off);
        if (lane == 0) s_qdotbk = v;
    }

    // a[c] = sum_d Qh[d] * Wk_h[d, c]; threads split columns (coalesced).
    const float* Wkh = Wk + (size_t)(h * D_H) * D_MOD;
    {
        float2 acc = {0.f, 0.f};
        #pragma unroll 8
        for (int d = 0; d < D_H; ++d) {
            float qd = s_Qh[d];
            float2 wv = ((const float2*)(Wkh + (size_t)d * D_MOD))[t];
            acc.x += qd * wv.x;
            acc.y += qd * wv.y;
        }
        s_a[2 * t] = acc.x;
        s_a[2 * t + 1] = acc.y;
    }
    __syncthreads();

    // scores: wave-per-landmark-row
    const float scale = 0.125f;  // 1/sqrt(64)
    for (int j = wave; j < KSEL; j += 4) {
        const float4* x4 =
            (const float4*)(skip + ((size_t)b * L_SEQ + s_idx[j]) * D_MOD);
        const float4* a4 = (const float4*)s_a;
        float4 xv0 = x4[lane * 2], xv1 = x4[lane * 2 + 1];
        float4 a0 = a4[lane * 2], a1 = a4[lane * 2 + 1];
        float sum = xv0.x * a0.x + xv0.y * a0.y + xv0.z * a0.z + xv0.w * a0.w +
                    xv1.x * a1.x + xv1.y * a1.y + xv1.z * a1.z + xv1.w * a1.w;
        #pragma unroll
        for (int off = 32; off > 0; off >>= 1) sum += __shfl_down(sum, off);
        if (lane == 0) s_scores[j] = (sum + s_qdotbk) * scale;
    }
    __syncthreads();

    // softmax over 100 (wave 0): lanes hold j=lane and j=lane+64
    if (wave == 0) {
        float v0 = (lane < KSEL) ? s_scores[lane] : -3.4e38f;
        float v1 = (lane + 64 < KSEL) ? s_scores[lane + 64] : -3.4e38f;
        float m = fmaxf(v0, v1);
        #pragma unroll
        for (int off = 32; off > 0; off >>= 1) m = fmaxf(m, __shfl_down(m, off));
        m = __shfl(m, 0);
        float e0 = (lane < KSEL) ? expf(v0 - m) : 0.f;
        float e1 = (lane + 64 < KSEL) ? expf(v1 - m) : 0.f;
        float s = e0 + e1;
        #pragma unroll
        for (int off = 32; off > 0; off >>= 1) s += __shfl_down(s, off);
        s = __shfl(s, 0);
        float inv = 1.f / s;
        if (lane < KSEL) s_p[lane] = e0 * inv;
        if (lane + 64 < KSEL) s_p[lane + 64] = e1 * inv;
    }
    __syncthreads();

    // y[c] = sum_j p_j x_j[c]; threads split columns (coalesced per j).
    {
        float2 acc = {0.f, 0.f};
        for (int j = 0; j < KSEL; ++j) {
            float pj = s_p[j];
            float2 xv =
                ((const float2*)(skip + ((size_t)b * L_SEQ + s_idx[j]) * D_MOD))[t];
            acc.x += pj * xv.x;
            acc.y += pj * xv.y;
        }
        s_y[2 * t] = acc.x;
        s_y[2 * t + 1] = acc.y;
    }
    __syncthreads();

    // attn_h = Wv_h @ y + bv_h; wave-per-row
    const float* Wvh = Wv + (size_t)(h * D_H) * D_MOD;
    for (int d = wave; d < D_H; d += 4) {
        const float4* row4 = (const float4*)(Wvh + (size_t)d * D_MOD);
        const float4* y4 = (const float4*)s_y;
        float4 w0 = row4[lane * 2], w1 = row4[lane * 2 + 1];
        float4 y0 = y4[lane * 2], y1 = y4[lane * 2 + 1];
        float sum = w0.x * y0.x + w0.y * y0.y + w0.z * y0.z + w0.w * y0.w +
                    w1.x * y1.x + w1.y * y1.y + w1.z * y1.z + w1.w * y1.w;
        #pragma unroll
        for (int off = 32; off > 0; off >>= 1) sum += __shfl_down(sum, off);
        if (lane == 0) attn_out[(size_t)b * D_MOD + h * D_H + d] = sum + bv[h * D_H + d];
    }
}

// ---------------------------------------------------------------------------
// Kernel 3: out = attn @ Wo.T + bo. Block = (row-chunk, batch); wave-per-row.
// ---------------------------------------------------------------------------
__global__ __launch_bounds__(256) void out_kernel(const float* __restrict__ attn,
                                                  const float* __restrict__ Wo,
                                                  const float* __restrict__ bo,
                                                  float* __restrict__ out) {
    const int b = blockIdx.x & 15;
    const int rc = blockIdx.x >> 4;
    const int t = threadIdx.x;
    const int lane = t & 63;
    const int wave = t >> 6;

    __shared__ float s_attn[D_MOD];
    for (int i = t; i < D_MOD; i += 256) s_attn[i] = attn[(size_t)b * D_MOD + i];
    __syncthreads();

    for (int d = wave; d < 64; d += 4) {
        const int r = rc * 64 + d;
        const float4* row4 = (const float4*)(Wo + (size_t)r * D_MOD);
        const float4* a4 = (const float4*)s_attn;
        float4 w0 = row4[lane * 2], w1 = row4[lane * 2 + 1];
        float4 a0 = a4[lane * 2], a1 = a4[lane * 2 + 1];
        float sum = w0.x * a0.x + w0.y * a0.y + w0.z * a0.z + w0.w * a0.w +
                    w1.x * a1.x + w1.y * a1.y + w1.z * a1.z + w1.w * a1.w;
        #pragma unroll
        for (int off = 32; off > 0; off >>= 1) sum += __shfl_down(sum, off);
        if (lane == 0) out[(size_t)b * D_MOD + r] = sum + bo[r];
    }
}

extern "C" void kernel_launch(void* const* d_in, const int* in_sizes, int n_in,
                              void* d_out, int out_size, void* d_ws, size_t ws_size,
                              hipStream_t stream) {
    const float* mamba = (const float*)d_in[0];
    const float* skip  = (const float*)d_in[1];
    const float* hw    = (const float*)d_in[2];
    const float* Wq    = (const float*)d_in[3];
    const float* bq    = (const float*)d_in[4];
    const float* Wk    = (const float*)d_in[5];
    const float* bk    = (const float*)d_in[6];
    const float* Wv    = (const float*)d_in[7];
    const float* bv    = (const float*)d_in[8];
    const float* Wo    = (const float*)d_in[9];
    const float* bo    = (const float*)d_in[10];
    float* out = (float*)d_out;

    int* idx = (int*)d_ws;                             // B*K ints = 6400 B
    float* attn = (float*)((char*)d_ws + 8192);        // B*D floats = 32 KB

    topk_kernel<<<B_SZ, 256, 0, stream>>>(hw, idx);
    attn_kernel<<<B_SZ * N_H, 256, 0, stream>>>(mamba, skip, Wq, bq, Wk, bk,
                                                Wv, bv, idx, attn);
    out_kernel<<<B_SZ * N_H, 256, 0, stream>>>(attn, Wo, bo, out);
}

// Round 2
// 464.168 us; speedup vs baseline: 1.1396x; 1.1396x over previous
//
#include <hip/hip_runtime.h>
#include <hip/hip_bf16.h>
#include <stdint.h>

#define B_SZ 16
#define L_SEQ 8192
#define D_MOD 512
#define N_H 8
#define D_H 64
#define KSEL 100

// ---------------------------------------------------------------------------
// Fused kernel: one block per (batch, head), 512 threads (8 waves).
//   phase 0: load query row + hawkes weights (bit patterns) into LDS
//   phase 1: Qh = Wq_h @ query + bq_h              (wave-per-row)
//   phase 2: a = Qh @ Wk_h (wave-split over d, LDS partial reduce)
//   phase 3: exact top-100 radix select on uval (redundant per head, parallel)
//   phase 4: ONE gather pass over the 100 landmark rows with online softmax:
//            each wave keeps running (m, l, acc) — scores+softmax+PV fused
//   phase 5: cross-wave softmax combine -> y; attn_h = Wv_h @ y + bv_h
// Landmark set is permutation-invariant downstream (softmax-weighted sum),
// so selection order doesn't matter; ties take lowest index (jax-stable).
// ---------------------------------------------------------------------------
__global__ __launch_bounds__(512) void fused_attn_kernel(
    const float* __restrict__ mamba, const float* __restrict__ skip,
    const float* __restrict__ w,
    const float* __restrict__ Wq, const float* __restrict__ bq,
    const float* __restrict__ Wk, const float* __restrict__ bk,
    const float* __restrict__ Wv, const float* __restrict__ bv,
    float* __restrict__ attn_out) {
    const int b = blockIdx.x >> 3;
    const int h = blockIdx.x & 7;
    const int t = threadIdx.x;
    const int lane = t & 63;
    const int wave = t >> 6;  // 0..7

    __shared__ uint32_t uval[L_SEQ];      // 32 KB
    __shared__ float s_part[8 * D_MOD];   // 16 KB (a-partials, then pv-partials)
    __shared__ float s_query[D_MOD];
    __shared__ float s_a[D_MOD];
    __shared__ float s_y[D_MOD];
    __shared__ float s_Qh[D_H];
    __shared__ int s_idx[128];
    __shared__ int hist[256];
    __shared__ int s_wtot[4];
    __shared__ float s_m[8], s_l[8];
    __shared__ uint32_t s_thresh;
    __shared__ int s_rem, s_cnt;
    __shared__ float s_qdotbk;

    // ---- phase 0: loads ----
    const float* qrow = mamba + ((size_t)b * L_SEQ + (L_SEQ - 1)) * D_MOD;
    if (t < D_MOD) s_query[t] = qrow[t];
    const float* wb = w + (size_t)b * L_SEQ;
    for (int i = t; i < L_SEQ; i += 512) uval[i] = __float_as_uint(wb[i]);
    __syncthreads();

    // ---- phase 1: Qh (wave-per-row, 8 rows per wave) ----
    const float* Wqh = Wq + (size_t)(h * D_H) * D_MOD;
    {
        const float4* q4 = (const float4*)s_query;
        float4 q0 = q4[lane * 2], q1 = q4[lane * 2 + 1];
        for (int d = wave; d < D_H; d += 8) {
            const float4* row4 = (const float4*)(Wqh + (size_t)d * D_MOD);
            float4 w0 = row4[lane * 2], w1 = row4[lane * 2 + 1];
            float sum = w0.x * q0.x + w0.y * q0.y + w0.z * q0.z + w0.w * q0.w +
                        w1.x * q1.x + w1.y * q1.y + w1.z * q1.z + w1.w * q1.w;
            #pragma unroll
            for (int off = 32; off > 0; off >>= 1) sum += __shfl_down(sum, off);
            if (lane == 0) s_Qh[d] = sum + bq[h * D_H + d];
        }
    }
    __syncthreads();

    // ---- phase 2: a[c] = sum_d Qh[d]*Wk_h[d,c], wave-split over d ----
    if (wave == 0) {  // also fold bk: qdotbk = Qh . bk_h
        float v = s_Qh[lane] * bk[h * D_H + lane];
        #pragma unroll
        for (int off = 32; off > 0; off >>= 1) v += __shfl_down(v, off);
        if (lane == 0) s_qdotbk = v;
    }
    {
        const float* Wkh = Wk + (size_t)(h * D_H) * D_MOD;
        float4 a0 = {0, 0, 0, 0}, a1 = {0, 0, 0, 0};
        #pragma unroll
        for (int dd = 0; dd < 8; ++dd) {
            const int d = wave * 8 + dd;
            float qd = s_Qh[d];
            const float4* row4 = (const float4*)(Wkh + (size_t)d * D_MOD);
            float4 w0 = row4[lane * 2], w1 = row4[lane * 2 + 1];
            a0.x += qd * w0.x; a0.y += qd * w0.y; a0.z += qd * w0.z; a0.w += qd * w0.w;
            a1.x += qd * w1.x; a1.y += qd * w1.y; a1.z += qd * w1.z; a1.w += qd * w1.w;
        }
        float4* p4 = (float4*)&s_part[wave * D_MOD + lane * 8];
        p4[0] = a0; p4[1] = a1;
    }
    __syncthreads();
    {
        float v = 0.f;
        #pragma unroll
        for (int ww = 0; ww < 8; ++ww) v += s_part[ww * D_MOD + t];
        s_a[t] = v;
    }

    // ---- phase 3: radix select top-100 ----
    uint32_t prefix = 0, pmask = 0;
    int remaining = KSEL;
    for (int pass = 0; pass < 4; ++pass) {
        const int shift = 24 - 8 * pass;
        if (t < 256) hist[t] = 0;
        __syncthreads();
        for (int i = t; i < L_SEQ; i += 512) {
            uint32_t u = uval[i];
            if ((u & pmask) == prefix) atomicAdd(&hist[(u >> shift) & 0xFF], 1);
        }
        __syncthreads();
        int v = 0;
        if (t < 256) {
            v = hist[t];
            #pragma unroll
            for (int off = 1; off < 64; off <<= 1) {
                int u = __shfl_down(v, off);
                if (lane + off < 64) v += u;
            }
            if (lane == 0) s_wtot[wave] = v;  // wave in 0..3 here
        }
        __syncthreads();
        if (t < 256) {
            int hi = 0;
            for (int w2 = wave + 1; w2 < 4; ++w2) hi += s_wtot[w2];
            int suff = v + hi;            // # elems in bins >= t (matching prefix)
            int suff_next = suff - hist[t];  // # elems in bins > t
            if (suff >= remaining && suff_next < remaining) {
                s_thresh = prefix | ((uint32_t)t << shift);
                s_rem = remaining - suff_next;
            }
        }
        __syncthreads();
        prefix = s_thresh;
        remaining = s_rem;
        pmask |= (uint32_t)0xFF << shift;
        __syncthreads();
    }

    if (t == 0) s_cnt = 0;
    __syncthreads();
    for (int i = t; i < L_SEQ; i += 512) {
        if (uval[i] > prefix) {
            int p = atomicAdd(&s_cnt, 1);
            s_idx[p] = i;
        }
    }
    __syncthreads();
    const int cntgt = s_cnt;  // == KSEL - remaining
    if (wave == 0) {  // take `remaining` lowest-index ties
        int needed = remaining;
        int taken = 0;
        for (int base = 0; base < L_SEQ && needed > 0; base += 64) {
            bool eq = (uval[base + lane] == prefix);
            unsigned long long mask = __ballot(eq);
            int before = __popcll(mask & ((1ull << lane) - 1ull));
            int c = __popcll(mask);
            int take = c < needed ? c : needed;
            if (eq && before < take) s_idx[cntgt + taken + before] = base + lane;
            taken += take;
            needed -= take;
        }
    }
    __syncthreads();

    // ---- phase 4: single gather pass with online softmax ----
    const float scale = 0.125f;  // 1/sqrt(64)
    {
        const float4* a4 = (const float4*)s_a;
        float4 av0 = a4[lane * 2], av1 = a4[lane * 2 + 1];
        float qdotbk = s_qdotbk;
        float m = -INFINITY, l = 0.f;
        float4 acc0 = {0, 0, 0, 0}, acc1 = {0, 0, 0, 0};
        for (int j = wave; j < KSEL; j += 8) {
            const float4* x4 =
                (const float4*)(skip + ((size_t)b * L_SEQ + s_idx[j]) * D_MOD);
            float4 x0 = x4[lane * 2], x1 = x4[lane * 2 + 1];
            float sum = x0.x * av0.x + x0.y * av0.y + x0.z * av0.z + x0.w * av0.w +
                        x1.x * av1.x + x1.y * av1.y + x1.z * av1.z + x1.w * av1.w;
            #pragma unroll
            for (int off = 32; off > 0; off >>= 1) sum += __shfl_xor(sum, off);
            float s = (sum + qdotbk) * scale;
            float mnew = fmaxf(m, s);
            float c = expf(m - mnew);   // 0 on first iter (m = -inf)
            float e = expf(s - mnew);
            l = l * c + e;
            acc0.x = acc0.x * c + e * x0.x; acc0.y = acc0.y * c + e * x0.y;
            acc0.z = acc0.z * c + e * x0.z; acc0.w = acc0.w * c + e * x0.w;
            acc1.x = acc1.x * c + e * x1.x; acc1.y = acc1.y * c + e * x1.y;
            acc1.z = acc1.z * c + e * x1.z; acc1.w = acc1.w * c + e * x1.w;
            m = mnew;
        }
        float4* p4 = (float4*)&s_part[wave * D_MOD + lane * 8];
        p4[0] = acc0; p4[1] = acc1;
        if (lane == 0) { s_m[wave] = m; s_l[wave] = l; }
    }
    __syncthreads();

    // ---- phase 5: cross-wave combine -> y, then attn_h = Wv_h @ y + bv_h ----
    {
        float mstar = -INFINITY;
        #pragma unroll
        for (int ww = 0; ww < 8; ++ww) mstar = fmaxf(mstar, s_m[ww]);
        float num = 0.f, den = 0.f;
        #pragma unroll
        for (int ww = 0; ww < 8; ++ww) {
            float sc = expf(s_m[ww] - mstar);
            num += sc * s_part[ww * D_MOD + t];
            den += sc * s_l[ww];
        }
        s_y[t] = num / den;
    }
    __syncthreads();

    const float* Wvh = Wv + (size_t)(h * D_H) * D_MOD;
    {
        const float4* y4 = (const float4*)s_y;
        float4 y0 = y4[lane * 2], y1 = y4[lane * 2 + 1];
        for (int d = wave; d < D_H; d += 8) {
            const float4* row4 = (const float4*)(Wvh + (size_t)d * D_MOD);
            float4 w0 = row4[lane * 2], w1 = row4[lane * 2 + 1];
            float sum = w0.x * y0.x + w0.y * y0.y + w0.z * y0.z + w0.w * y0.w +
                        w1.x * y1.x + w1.y * y1.y + w1.z * y1.z + w1.w * y1.w;
            #pragma unroll
            for (int off = 32; off > 0; off >>= 1) sum += __shfl_down(sum, off);
            if (lane == 0)
                attn_out[(size_t)b * D_MOD + h * D_H + d] = sum + bv[h * D_H + d];
        }
    }
}

// ---------------------------------------------------------------------------
// out = attn @ Wo.T + bo. Block = (row-chunk, batch); wave-per-row.
// ---------------------------------------------------------------------------
__global__ __launch_bounds__(256) void out_kernel(const float* __restrict__ attn,
                                                  const float* __restrict__ Wo,
                                                  const float* __restrict__ bo,
                                                  float* __restrict__ out) {
    const int b = blockIdx.x & 15;
    const int rc = blockIdx.x >> 4;
    const int t = threadIdx.x;
    const int lane = t & 63;
    const int wave = t >> 6;

    __shared__ float s_attn[D_MOD];
    for (int i = t; i < D_MOD; i += 256) s_attn[i] = attn[(size_t)b * D_MOD + i];
    __syncthreads();

    const float4* a4 = (const float4*)s_attn;
    float4 a0 = a4[lane * 2], a1 = a4[lane * 2 + 1];
    for (int d = wave; d < 64; d += 4) {
        const int r = rc * 64 + d;
        const float4* row4 = (const float4*)(Wo + (size_t)r * D_MOD);
        float4 w0 = row4[lane * 2], w1 = row4[lane * 2 + 1];
        float sum = w0.x * a0.x + w0.y * a0.y + w0.z * a0.z + w0.w * a0.w +
                    w1.x * a1.x + w1.y * a1.y + w1.z * a1.z + w1.w * a1.w;
        #pragma unroll
        for (int off = 32; off > 0; off >>= 1) sum += __shfl_down(sum, off);
        if (lane == 0) out[(size_t)b * D_MOD + r] = sum + bo[r];
    }
}

extern "C" void kernel_launch(void* const* d_in, const int* in_sizes, int n_in,
                              void* d_out, int out_size, void* d_ws, size_t ws_size,
                              hipStream_t stream) {
    const float* mamba = (const float*)d_in[0];
    const float* skip  = (const float*)d_in[1];
    const float* hw    = (const float*)d_in[2];
    const float* Wq    = (const float*)d_in[3];
    const float* bq    = (const float*)d_in[4];
    const float* Wk    = (const float*)d_in[5];
    const float* bk    = (const float*)d_in[6];
    const float* Wv    = (const float*)d_in[7];
    const float* bv    = (const float*)d_in[8];
    const float* Wo    = (const float*)d_in[9];
    const float* bo    = (const float*)d_in[10];
    float* out = (float*)d_out;

    float* attn = (float*)d_ws;  // B*D floats = 32 KB

    fused_attn_kernel<<<B_SZ * N_H, 512, 0, stream>>>(mamba, skip, hw, Wq, bq,
                                                      Wk, bk, Wv, bv, attn);
    out_kernel<<<B_SZ * N_H, 256, 0, stream>>>(attn, Wo, bo, out);
}

// Round 3
// 455.814 us; speedup vs baseline: 1.1604x; 1.0183x over previous
//
#include <hip/hip_runtime.h>
#include <hip/hip_bf16.h>
#include <stdint.h>

#define B_SZ 16
#define L_SEQ 8192
#define D_MOD 512
#define N_H 8
#define D_H 64
#define KSEL 100

// ---------------------------------------------------------------------------
// Fully fused kernel: one block per (batch, head), 512 threads (8 waves).
//   phase 0: load query row + hawkes weight bit patterns into LDS
//   phase 1: Qh = Wq_h @ query + bq_h                  (wave-per-row)
//   phase 2: a = Qh @ Wk_h (wave-split over d, LDS partial reduce)
//   phase 3: exact top-100 radix select (redundant per head — free, parallel)
//   phase 4: ONE software-pipelined gather pass over the 100 landmark rows
//            with online softmax (scores+softmax+PV fused)
//   phase 5: cross-wave softmax combine -> y; attn_h = Wv_h @ y + bv_h (LDS)
//   phase 6: out partial: atomicAdd(Wo[:,h*64:+64] @ attn_h (+bo if h==0))
// d_out is zeroed via hipMemsetAsync before launch.
// Landmark set is permutation-invariant downstream (softmax-weighted sum),
// so selection order doesn't matter; ties take lowest index (jax-stable).
// ---------------------------------------------------------------------------
__global__ __launch_bounds__(512) void fused_attn_kernel(
    const float* __restrict__ mamba, const float* __restrict__ skip,
    const float* __restrict__ w,
    const float* __restrict__ Wq, const float* __restrict__ bq,
    const float* __restrict__ Wk, const float* __restrict__ bk,
    const float* __restrict__ Wv, const float* __restrict__ bv,
    const float* __restrict__ Wo, const float* __restrict__ bo,
    float* __restrict__ out) {
    const int b = blockIdx.x >> 3;
    const int h = blockIdx.x & 7;
    const int t = threadIdx.x;
    const int lane = t & 63;
    const int wave = t >> 6;  // 0..7

    __shared__ uint32_t uval[L_SEQ];      // 32 KB
    __shared__ float s_part[8 * D_MOD];   // 16 KB (a-partials, then pv-partials)
    __shared__ float s_query[D_MOD];
    __shared__ float s_a[D_MOD];
    __shared__ float s_y[D_MOD];
    __shared__ float s_Qh[D_H];
    __shared__ float s_ah[D_H];
    __shared__ int s_idx[128];
    __shared__ int s_eq[128];
    __shared__ int hist[256];
    __shared__ int s_wtot[4];
    __shared__ float s_m[8], s_l[8];
    __shared__ uint32_t s_thresh;
    __shared__ int s_rem, s_cnt, s_ecnt;
    __shared__ float s_qdotbk;

    // ---- phase 0: loads ----
    const float* qrow = mamba + ((size_t)b * L_SEQ + (L_SEQ - 1)) * D_MOD;
    if (t < D_MOD) s_query[t] = qrow[t];
    const float* wb = w + (size_t)b * L_SEQ;
    for (int i = t; i < L_SEQ; i += 512) uval[i] = __float_as_uint(wb[i]);
    __syncthreads();

    // ---- phase 1: Qh (wave-per-row, 8 rows per wave) ----
    const float* Wqh = Wq + (size_t)(h * D_H) * D_MOD;
    {
        const float4* q4 = (const float4*)s_query;
        float4 q0 = q4[lane * 2], q1 = q4[lane * 2 + 1];
        for (int d = wave; d < D_H; d += 8) {
            const float4* row4 = (const float4*)(Wqh + (size_t)d * D_MOD);
            float4 w0 = row4[lane * 2], w1 = row4[lane * 2 + 1];
            float sum = w0.x * q0.x + w0.y * q0.y + w0.z * q0.z + w0.w * q0.w +
                        w1.x * q1.x + w1.y * q1.y + w1.z * q1.z + w1.w * q1.w;
            #pragma unroll
            for (int off = 32; off > 0; off >>= 1) sum += __shfl_down(sum, off);
            if (lane == 0) s_Qh[d] = sum + bq[h * D_H + d];
        }
    }
    __syncthreads();

    // ---- phase 2: a[c] = sum_d Qh[d]*Wk_h[d,c], wave-split over d ----
    if (wave == 0) {  // also fold bk: qdotbk = Qh . bk_h
        float v = s_Qh[lane] * bk[h * D_H + lane];
        #pragma unroll
        for (int off = 32; off > 0; off >>= 1) v += __shfl_down(v, off);
        if (lane == 0) s_qdotbk = v;
    }
    {
        const float* Wkh = Wk + (size_t)(h * D_H) * D_MOD;
        float4 a0 = {0, 0, 0, 0}, a1 = {0, 0, 0, 0};
        #pragma unroll
        for (int dd = 0; dd < 8; ++dd) {
            const int d = wave * 8 + dd;
            float qd = s_Qh[d];
            const float4* row4 = (const float4*)(Wkh + (size_t)d * D_MOD);
            float4 w0 = row4[lane * 2], w1 = row4[lane * 2 + 1];
            a0.x += qd * w0.x; a0.y += qd * w0.y; a0.z += qd * w0.z; a0.w += qd * w0.w;
            a1.x += qd * w1.x; a1.y += qd * w1.y; a1.z += qd * w1.z; a1.w += qd * w1.w;
        }
        float4* p4 = (float4*)&s_part[wave * D_MOD + lane * 8];
        p4[0] = a0; p4[1] = a1;
    }
    __syncthreads();
    {
        float v = 0.f;
        #pragma unroll
        for (int ww = 0; ww < 8; ++ww) v += s_part[ww * D_MOD + t];
        s_a[t] = v;
    }

    // ---- phase 3: radix select top-100 ----
    uint32_t prefix = 0, pmask = 0;
    int remaining = KSEL;
    for (int pass = 0; pass < 4; ++pass) {
        const int shift = 24 - 8 * pass;
        if (t < 256) hist[t] = 0;
        __syncthreads();
        for (int i = t; i < L_SEQ; i += 512) {
            uint32_t u = uval[i];
            if ((u & pmask) == prefix) atomicAdd(&hist[(u >> shift) & 0xFF], 1);
        }
        __syncthreads();
        int v = 0;
        if (t < 256) {
            v = hist[t];
            #pragma unroll
            for (int off = 1; off < 64; off <<= 1) {
                int u = __shfl_down(v, off);
                if (lane + off < 64) v += u;
            }
            if (lane == 0) s_wtot[wave] = v;  // wave in 0..3 here
        }
        __syncthreads();
        if (t < 256) {
            int hi = 0;
            for (int w2 = wave + 1; w2 < 4; ++w2) hi += s_wtot[w2];
            int suff = v + hi;               // # elems in bins >= t (matching prefix)
            int suff_next = suff - hist[t];  // # elems in bins > t
            if (suff >= remaining && suff_next < remaining) {
                s_thresh = prefix | ((uint32_t)t << shift);
                s_rem = remaining - suff_next;
            }
        }
        __syncthreads();
        prefix = s_thresh;
        remaining = s_rem;
        pmask |= (uint32_t)0xFF << shift;
        __syncthreads();
    }

    if (t == 0) { s_cnt = 0; s_ecnt = 0; }
    __syncthreads();
    // collect > threshold, and equal-to-threshold candidates
    for (int i = t; i < L_SEQ; i += 512) {
        uint32_t u = uval[i];
        if (u > prefix) {
            int p = atomicAdd(&s_cnt, 1);
            s_idx[p] = i;
        } else if (u == prefix) {
            int p = atomicAdd(&s_ecnt, 1);
            if (p < 128) s_eq[p] = i;
        }
    }
    __syncthreads();
    const int cntgt = s_cnt;  // == KSEL - remaining
    if (wave == 0) {  // take `remaining` lowest-index ties via shfl-min extraction
        int n = s_ecnt < 128 ? s_ecnt : 128;
        int taken_val = -1;
        for (int r = 0; r < remaining; ++r) {
            int mymin = 0x7FFFFFFF;
            for (int i = lane; i < n; i += 64) {
                int e = s_eq[i];
                if (e > taken_val && e < mymin) mymin = e;
            }
            #pragma unroll
            for (int off = 32; off > 0; off >>= 1) {
                int o = __shfl_xor(mymin, off);
                mymin = o < mymin ? o : mymin;
            }
            if (lane == 0) s_idx[cntgt + r] = mymin;
            taken_val = mymin;  // butterfly leaves min on all lanes
        }
    }
    __syncthreads();

    // ---- phase 4: software-pipelined gather with online softmax ----
    const float scale = 0.125f;  // 1/sqrt(64)
    {
        const float4* a4 = (const float4*)s_a;
        float4 av0 = a4[lane * 2], av1 = a4[lane * 2 + 1];
        float qdotbk = s_qdotbk;
        float m = -INFINITY, l = 0.f;
        float4 acc0 = {0, 0, 0, 0}, acc1 = {0, 0, 0, 0};
        int j = wave;
        float4 x0 = {0, 0, 0, 0}, x1 = {0, 0, 0, 0};
        if (j < KSEL) {
            const float4* x4 =
                (const float4*)(skip + ((size_t)b * L_SEQ + s_idx[j]) * D_MOD);
            x0 = x4[lane * 2]; x1 = x4[lane * 2 + 1];
        }
        while (j < KSEL) {
            const int jn = j + 8;
            float4 n0 = {0, 0, 0, 0}, n1 = {0, 0, 0, 0};
            if (jn < KSEL) {  // prefetch next row while reducing current
                const float4* x4 =
                    (const float4*)(skip + ((size_t)b * L_SEQ + s_idx[jn]) * D_MOD);
                n0 = x4[lane * 2]; n1 = x4[lane * 2 + 1];
            }
            float sum = x0.x * av0.x + x0.y * av0.y + x0.z * av0.z + x0.w * av0.w +
                        x1.x * av1.x + x1.y * av1.y + x1.z * av1.z + x1.w * av1.w;
            #pragma unroll
            for (int off = 32; off > 0; off >>= 1) sum += __shfl_xor(sum, off);
            float s = (sum + qdotbk) * scale;
            float mnew = fmaxf(m, s);
            float c = expf(m - mnew);  // 0 on first iter (m = -inf)
            float e = expf(s - mnew);
            l = l * c + e;
            acc0.x = acc0.x * c + e * x0.x; acc0.y = acc0.y * c + e * x0.y;
            acc0.z = acc0.z * c + e * x0.z; acc0.w = acc0.w * c + e * x0.w;
            acc1.x = acc1.x * c + e * x1.x; acc1.y = acc1.y * c + e * x1.y;
            acc1.z = acc1.z * c + e * x1.z; acc1.w = acc1.w * c + e * x1.w;
            m = mnew;
            x0 = n0; x1 = n1;
            j = jn;
        }
        float4* p4 = (float4*)&s_part[wave * D_MOD + lane * 8];
        p4[0] = acc0; p4[1] = acc1;
        if (lane == 0) { s_m[wave] = m; s_l[wave] = l; }
    }
    __syncthreads();

    // ---- phase 5: cross-wave combine -> y, then attn_h = Wv_h @ y + bv_h ----
    {
        float mstar = -INFINITY;
        #pragma unroll
        for (int ww = 0; ww < 8; ++ww) mstar = fmaxf(mstar, s_m[ww]);
        float num = 0.f, den = 0.f;
        #pragma unroll
        for (int ww = 0; ww < 8; ++ww) {
            float sc = expf(s_m[ww] - mstar);
            num += sc * s_part[ww * D_MOD + t];
            den += sc * s_l[ww];
        }
        s_y[t] = num / den;
    }
    __syncthreads();

    const float* Wvh = Wv + (size_t)(h * D_H) * D_MOD;
    {
        const float4* y4 = (const float4*)s_y;
        float4 y0 = y4[lane * 2], y1 = y4[lane * 2 + 1];
        for (int d = wave; d < D_H; d += 8) {
            const float4* row4 = (const float4*)(Wvh + (size_t)d * D_MOD);
            float4 w0 = row4[lane * 2], w1 = row4[lane * 2 + 1];
            float sum = w0.x * y0.x + w0.y * y0.y + w0.z * y0.z + w0.w * y0.w +
                        w1.x * y1.x + w1.y * y1.y + w1.z * y1.z + w1.w * y1.w;
            #pragma unroll
            for (int off = 32; off > 0; off >>= 1) sum += __shfl_down(sum, off);
            if (lane == 0) s_ah[d] = sum + bv[h * D_H + d];
        }
    }
    __syncthreads();

    // ---- phase 6: out partial = Wo[:, h*64:(h+1)*64] @ attn_h, atomicAdd ----
    {
        const float4* wrow = (const float4*)(Wo + (size_t)t * D_MOD + h * D_H);
        const float4* ah4 = (const float4*)s_ah;
        float acc = 0.f;
        #pragma unroll
        for (int i = 0; i < 16; ++i) {
            float4 wv = wrow[i];
            float4 av = ah4[i];
            acc += wv.x * av.x + wv.y * av.y + wv.z * av.z + wv.w * av.w;
        }
        if (h == 0) acc += bo[t];
        atomicAdd(&out[(size_t)b * D_MOD + t], acc);
    }
}

extern "C" void kernel_launch(void* const* d_in, const int* in_sizes, int n_in,
                              void* d_out, int out_size, void* d_ws, size_t ws_size,
                              hipStream_t stream) {
    const float* mamba = (const float*)d_in[0];
    const float* skip  = (const float*)d_in[1];
    const float* hw    = (const float*)d_in[2];
    const float* Wq    = (const float*)d_in[3];
    const float* bq    = (const float*)d_in[4];
    const float* Wk    = (const float*)d_in[5];
    const float* bk    = (const float*)d_in[6];
    const float* Wv    = (const float*)d_in[7];
    const float* bv    = (const float*)d_in[8];
    const float* Wo    = (const float*)d_in[9];
    const float* bo    = (const float*)d_in[10];
    float* out = (float*)d_out;

    hipMemsetAsync(out, 0, (size_t)out_size * sizeof(float), stream);
    fused_attn_kernel<<<B_SZ * N_H, 512, 0, stream>>>(mamba, skip, hw, Wq, bq,
                                                      Wk, bk, Wv, bv, Wo, bo, out);
}